// Round 15
// baseline (114.705 us; speedup 1.0000x reference)
//
#include <hip/hip_runtime.h>
#include <math.h>

#define B_    16
#define CIN   64
#define COUT  128
#define H_    128
#define W_    128
#define CI2   128            // 2*CIN (x ++ silu(x))
#define KTOT  1152           // 9 taps * CI2

typedef __bf16 bf16x8 __attribute__((ext_vector_type(8)));
typedef float  f32x4  __attribute__((ext_vector_type(4)));

#define XT_BYTES  ((size_t)B_ * H_ * W_ * CI2 * 2)   // 67,108,864
#define WC_BYTES  ((size_t)COUT * KTOT * 2)          // 294,912
#define Z_OFF     (XT_BYTES + WC_BYTES)
#define WS_NEED   (Z_OFF + 4096)

// ---------- prep 1: weights -> Wc, HALF-TAP-MAJOR wave-fragment order ----------
// half hh = tap*2 + (ks>>1) in [0,18); frag f = (wm*4+m)*2 + (ks&1) in [0,16)
// elem off = (hh*16 + f)*512 + lane*8 + e  -> 16KB contiguous per half.
__global__ __launch_bounds__(256) void w_prep(const float* __restrict__ sw,
                                              const float* __restrict__ bw,
                                              __bf16* __restrict__ wc,
                                              float* __restrict__ zp) {
    const int i = blockIdx.x * 256 + threadIdx.x;
    if (blockIdx.x == 0) zp[threadIdx.x] = 0.f;  // zeros page (1 KiB)
    if (i >= COUT * KTOT) return;
    const int co = i / KTOT, k = i - co * KTOT;
    const int tap = k >> 7, ci2 = k & 127;
    float v;
    if (ci2 < CIN) {
        const float* p = sw + ((size_t)(co * CIN + ci2) * 9 + tap) * 4;
        v = p[0] + p[1] + p[2] + p[3];
    } else {
        v = bw[(size_t)(co * CIN + (ci2 - CIN)) * 9 + tap];
    }
    const int wm = co >> 6, m = (co >> 4) & 3, l15 = co & 15;
    const int ks = (k >> 5) & 3, lq = (k >> 3) & 3, e = k & 7;
    const int hh = tap * 2 + (ks >> 1);
    const int f  = (wm * 4 + m) * 2 + (ks & 1);
    const size_t off = ((size_t)(hh * 16 + f)) * 512 + (lq * 16 + l15) * 8 + e;
    wc[off] = (__bf16)v;
}

// ---------- prep 2: x (NCHW fp32) -> Xt (NHWC bf16, ci2 = x ++ silu(x)) ----------
__global__ __launch_bounds__(256) void xt_prep(const float* __restrict__ x,
                                               __bf16* __restrict__ xt) {
    __shared__ __align__(16) __bf16 tile[64][136];
    const int t  = threadIdx.x;
    const int w0 = blockIdx.x * 64;
    const int h  = blockIdx.y;
    const int b  = blockIdx.z;
    const float* xb = x + ((size_t)(b * CIN) * H_ + h) * W_ + w0;
#pragma unroll
    for (int rep = 0; rep < 16; ++rep) {
        const int idx = rep * 256 + t;
        const int ci = idx >> 6, w = idx & 63;
        const float v = xb[(size_t)ci * H_ * W_ + w];
        tile[w][ci]       = (__bf16)v;
        tile[w][CIN + ci] = (__bf16)(v / (1.f + __expf(-v)));
    }
    __syncthreads();
    __bf16* ob = xt + (((size_t)b * H_ + h) * W_ + w0) * CI2;
#pragma unroll
    for (int rep = 0; rep < 4; ++rep) {
        const int idx = rep * 256 + t;
        const int w = idx >> 4, sl = idx & 15;
        *(bf16x8*)(ob + (size_t)w * CI2 + sl * 8) = *(const bf16x8*)(&tile[w][sl * 8]);
    }
}

// ---------- main: implicit-GEMM MFMA conv, 2-phase pipelined A staging ----------
// block: 128 couts x (8h x 16w); 4 waves 2(m) x 2(n).
// LDS: B halo 46KB + A half-tap double buffer 2x16KB = 78848B -> 2 blocks/CU.
// per half-tap: {issue stage(next 16KB) -> compute 2 ks (32 MFMA) -> barrier}.
__global__ __launch_bounds__(256, 2) void kan_mfma(const __bf16* __restrict__ xt,
                                                   const __bf16* __restrict__ wc,
                                                   const float* __restrict__ zp,
                                                   float* __restrict__ out) {
    __shared__ __align__(16) char xs[2880 * 16];    // B halo: 180 pos * 256B
    __shared__ __align__(16) char asA[1024 * 16];   // A half buffer A: 16 KB
    __shared__ __align__(16) char asB[1024 * 16];   // A half buffer B: 16 KB
    const int t    = threadIdx.x;
    const int lane = t & 63, wave = t >> 6;
    const int wm = wave >> 1, wn = wave & 1;
    const int l15 = lane & 15, lq = lane >> 4;

    // XCD-chunked bijective swizzle (2048 % 8 == 0)
    const int orig = blockIdx.x;
    const int wid  = (orig & 7) * 256 + (orig >> 3);
    const int b  = wid >> 7;
    const int hy = (wid & 127) >> 3, wx = wid & 7;
    const int w0 = wx * 16, h0 = hy * 8;

    // ---- stage B halo tile once (swizzled source, linear LDS dest)
    const size_t xbase = (size_t)b * (H_ * W_ * CI2);
#pragma unroll
    for (int i = 0; i < 12; ++i) {
        const int s = i * 256 + t;
        if (s < 2880) {
            const int pos = s >> 4, q = s & 15;
            const int ih = pos / 18, iw = pos - ih * 18;
            const int gh = h0 + ih - 1, gw = w0 + iw - 1;
            const int chunk = q ^ (pos & 15);
            const void* src;
            if (gh >= 0 && gh < H_ && gw >= 0 && gw < W_)
                src = (const void*)(xt + xbase + ((size_t)(gh * W_ + gw)) * CI2 + chunk * 8);
            else
                src = (const void*)zp;
            __builtin_amdgcn_global_load_lds(
                (const __attribute__((address_space(1))) unsigned int*)src,
                (__attribute__((address_space(3))) unsigned int*)(xs + s * 16), 16, 0, 0);
        }
    }

    // ---- stage one 16KB A-half (1024 x 16B, linear both sides)
#define STAGEH_(buf, hh)                                                        \
    _Pragma("unroll")                                                           \
    for (int i = 0; i < 4; ++i) {                                               \
        const int s = i * 256 + t;                                              \
        __builtin_amdgcn_global_load_lds(                                       \
            (const __attribute__((address_space(1))) unsigned int*)              \
                (wc + (size_t)(hh) * 8192 + s * 8),                             \
            (__attribute__((address_space(3))) unsigned int*)((buf) + s * 16),  \
            16, 0, 0);                                                          \
    }

    // ---- compute 2 ks-slices (32 MFMA) with A from `buf`
#define COMPUTE2_(buf, kss)                                                     \
    _Pragma("unroll")                                                           \
    for (int k2 = 0; k2 < 2; ++k2) {                                            \
        const int ks = (kss) + k2;                                              \
        bf16x8 af[4], bfr[4];                                                   \
        _Pragma("unroll")                                                       \
        for (int m = 0; m < 4; ++m)                                             \
            af[m] = *(const bf16x8*)((buf) +                                    \
                ((wm * 4 + m) * 2 + (ks & 1)) * 1024 + lane * 16);              \
        _Pragma("unroll")                                                       \
        for (int n = 0; n < 4; ++n) {                                           \
            const int pos_ = pos0[n] + dpos;                                    \
            const int swz_ = (ks * 4 + lq) ^ (pos_ & 15);                       \
            bfr[n] = *(const bf16x8*)(xs + pos_ * 256 + swz_ * 16);             \
        }                                                                       \
        _Pragma("unroll")                                                       \
        for (int m = 0; m < 4; ++m)                                             \
            _Pragma("unroll")                                                   \
            for (int n = 0; n < 4; ++n)                                         \
                acc[m][n] = __builtin_amdgcn_mfma_f32_16x16x32_bf16(            \
                    af[m], bfr[n], acc[m][n], 0, 0, 0);                         \
    }

    STAGEH_(asA, 0);
    __syncthreads();                 // B + A-half 0 ready

    f32x4 acc[4][4] = {};
    int pos0[4];
#pragma unroll
    for (int n = 0; n < 4; ++n) pos0[n] = (wn * 4 + n) * 18 + l15;

#pragma unroll 1
    for (int tap = 0; tap < 9; ++tap) {
        const int kh = (tap * 11) >> 5;          // tap/3 for 0..8
        const int kw = tap - kh * 3;
        const int dpos = kh * 18 + kw;

        // phase 0: stage half(tap*2+1) into asB; compute ks{0,1} from asA
        STAGEH_(asB, tap * 2 + 1);
        COMPUTE2_(asA, 0);
        __syncthreads();             // drains stage; asB ready; asA free

        // phase 1: stage half(tap*2+2) into asA; compute ks{2,3} from asB
        if (tap < 8) STAGEH_(asA, tap * 2 + 2);
        COMPUTE2_(asB, 2);
        __syncthreads();             // drains stage; asA ready; asB free
    }

    // ---- epilogue: D row = co (lq*4+r), col = position (l15); 64B store rows
    float* ob = out + (size_t)b * COUT * H_ * W_;
#pragma unroll
    for (int m = 0; m < 4; ++m) {
        const int co = wm * 64 + m * 16 + lq * 4;
#pragma unroll
        for (int n = 0; n < 4; ++n) {
            const int ph = wn * 4 + n;
            float* p = ob + ((size_t)co * H_ + (h0 + ph)) * W_ + (w0 + l15);
#pragma unroll
            for (int r = 0; r < 4; ++r)
                p[(size_t)r * H_ * W_] = acc[m][n][r];
        }
    }
#undef STAGEH_
#undef COMPUTE2_
}

// ---------- fallback (round-0 fp32 path, used only if ws too small) ----------
#define TS   16
#define COB  8
#define TIN  18
__global__ __launch_bounds__(256) void spline_sum_kernel(const float* __restrict__ sw,
                                                         float* __restrict__ wsum) {
    int i = blockIdx.x * 256 + threadIdx.x;
    if (i < COUT * CIN * 9) {
        const float4 v = *reinterpret_cast<const float4*>(sw + (size_t)i * 4);
        wsum[i] = v.x + v.y + v.z + v.w;
    }
}
__global__ __launch_bounds__(256) void kan_conv(const float* __restrict__ x,
                                                const float* __restrict__ wsp,
                                                const float* __restrict__ wb,
                                                float* __restrict__ out) {
    __shared__ float xsm[TIN][20];
    __shared__ float ssm[TIN][20];
    const int t = threadIdx.x, tx = t & 15, ty = t >> 4;
    const int w0 = (blockIdx.x & 7) * TS, h0 = (blockIdx.x >> 3) * TS;
    const int co0 = blockIdx.y * COB, b = blockIdx.z;
    float acc[COB];
#pragma unroll
    for (int i = 0; i < COB; ++i) acc[i] = 0.f;
    const float* xb = x + (size_t)b * CIN * H_ * W_;
    for (int ci = 0; ci < CIN; ++ci) {
        __syncthreads();
        const float* xc = xb + (size_t)ci * H_ * W_;
        for (int p = t; p < TIN * TIN; p += 256) {
            int r = p / TIN, c = p - r * TIN;
            int ih = h0 + r - 1, iw = w0 + c - 1;
            float v = 0.f;
            if (ih >= 0 && ih < H_ && iw >= 0 && iw < W_) v = xc[ih * W_ + iw];
            xsm[r][c] = v;
            ssm[r][c] = v / (1.f + expf(-v));
        }
        __syncthreads();
        float xv[9], sv[9];
#pragma unroll
        for (int kh = 0; kh < 3; ++kh)
#pragma unroll
            for (int kw = 0; kw < 3; ++kw) {
                xv[kh * 3 + kw] = xsm[ty + kh][tx + kw];
                sv[kh * 3 + kw] = ssm[ty + kh][tx + kw];
            }
#pragma unroll
        for (int co = 0; co < COB; ++co) {
            const float* w1 = wsp + ((size_t)(co0 + co) * CIN + ci) * 9;
            const float* w2 = wb  + ((size_t)(co0 + co) * CIN + ci) * 9;
#pragma unroll
            for (int k = 0; k < 9; ++k)
                acc[co] += xv[k] * w1[k] + sv[k] * w2[k];
        }
    }
    const int oh = h0 + ty, ow = w0 + tx;
#pragma unroll
    for (int co = 0; co < COB; ++co)
        out[(((size_t)b * COUT + (co0 + co)) * H_ + oh) * W_ + ow] = acc[co];
}

extern "C" void kernel_launch(void* const* d_in, const int* in_sizes, int n_in,
                              void* d_out, int out_size, void* d_ws, size_t ws_size,
                              hipStream_t stream) {
    const float* x  = (const float*)d_in[0];
    const float* sw = (const float*)d_in[1];   // (COUT,CIN,3,3,4)
    const float* bw = (const float*)d_in[2];   // (COUT,CIN,3,3)
    float* out = (float*)d_out;

    if (ws_size >= WS_NEED) {
        __bf16* xt = (__bf16*)d_ws;
        __bf16* wc = (__bf16*)((char*)d_ws + XT_BYTES);
        float*  zp = (float*)((char*)d_ws + Z_OFF);
        w_prep<<<(COUT * KTOT + 255) / 256, 256, 0, stream>>>(sw, bw, wc, zp);
        xt_prep<<<dim3(2, H_, B_), 256, 0, stream>>>(x, xt);
        kan_mfma<<<dim3(2048), 256, 0, stream>>>(xt, wc, zp, out);
    } else {
        float* wsum = (float*)d_ws;
        spline_sum_kernel<<<(COUT * CIN * 9 + 255) / 256, 256, 0, stream>>>(sw, wsum);
        kan_conv<<<dim3(64, COUT / COB, B_), 256, 0, stream>>>(x, wsum, bw, out);
    }
}

// Round 16
// 108.628 us; speedup vs baseline: 1.0559x; 1.0559x over previous
//
#include <hip/hip_runtime.h>
#include <math.h>

#define B_    16
#define CIN   64
#define COUT  128
#define H_    128
#define W_    128
#define CI2   128            // 2*CIN (x ++ silu(x))
#define KTOT  1152           // 9 taps * CI2

typedef __bf16 bf16x8 __attribute__((ext_vector_type(8)));
typedef float  f32x4  __attribute__((ext_vector_type(4)));

#define XT_BYTES  ((size_t)B_ * H_ * W_ * CI2 * 2)   // 67,108,864
#define WC_BYTES  ((size_t)COUT * KTOT * 2)          // 294,912
#define Z_OFF     (XT_BYTES + WC_BYTES)
#define WS_NEED   (Z_OFF + 4096)

// ---------- prep 1: weights -> Wc, HALF-TAP-MAJOR wave-fragment order ----------
// half hh = tap*2 + (ks>>1) in [0,18); frag f = (wm*4+m)*2 + (ks&1) in [0,16)
// elem off = (hh*16 + f)*512 + lane*8 + e  -> 16KB contiguous per half.
__global__ __launch_bounds__(256) void w_prep(const float* __restrict__ sw,
                                              const float* __restrict__ bw,
                                              __bf16* __restrict__ wc,
                                              float* __restrict__ zp) {
    const int i = blockIdx.x * 256 + threadIdx.x;
    if (blockIdx.x == 0) zp[threadIdx.x] = 0.f;  // zeros page (1 KiB)
    if (i >= COUT * KTOT) return;
    const int co = i / KTOT, k = i - co * KTOT;
    const int tap = k >> 7, ci2 = k & 127;
    float v;
    if (ci2 < CIN) {
        const float* p = sw + ((size_t)(co * CIN + ci2) * 9 + tap) * 4;
        v = p[0] + p[1] + p[2] + p[3];
    } else {
        v = bw[(size_t)(co * CIN + (ci2 - CIN)) * 9 + tap];
    }
    const int wm = co >> 6, m = (co >> 4) & 3, l15 = co & 15;
    const int ks = (k >> 5) & 3, lq = (k >> 3) & 3, e = k & 7;
    const int hh = tap * 2 + (ks >> 1);
    const int f  = (wm * 4 + m) * 2 + (ks & 1);
    const size_t off = ((size_t)(hh * 16 + f)) * 512 + (lq * 16 + l15) * 8 + e;
    wc[off] = (__bf16)v;
}

// ---------- prep 2: x (NCHW fp32) -> Xt (NHWC bf16, ci2 = x ++ silu(x)) ----------
__global__ __launch_bounds__(256) void xt_prep(const float* __restrict__ x,
                                               __bf16* __restrict__ xt) {
    __shared__ __align__(16) __bf16 tile[64][136];
    const int t  = threadIdx.x;
    const int w0 = blockIdx.x * 64;
    const int h  = blockIdx.y;
    const int b  = blockIdx.z;
    const float* xb = x + ((size_t)(b * CIN) * H_ + h) * W_ + w0;
#pragma unroll
    for (int rep = 0; rep < 16; ++rep) {
        const int idx = rep * 256 + t;
        const int ci = idx >> 6, w = idx & 63;
        const float v = xb[(size_t)ci * H_ * W_ + w];
        tile[w][ci]       = (__bf16)v;
        tile[w][CIN + ci] = (__bf16)(v / (1.f + __expf(-v)));
    }
    __syncthreads();
    __bf16* ob = xt + (((size_t)b * H_ + h) * W_ + w0) * CI2;
#pragma unroll
    for (int rep = 0; rep < 4; ++rep) {
        const int idx = rep * 256 + t;
        const int w = idx >> 4, sl = idx & 15;
        *(bf16x8*)(ob + (size_t)w * CI2 + sl * 8) = *(const bf16x8*)(&tile[w][sl * 8]);
    }
}

// ---------- main: implicit-GEMM MFMA conv, 2-phase + B-prefetch + setprio ----------
// block: 128 couts x (8h x 16w); 4 waves 2(m) x 2(n).
// LDS: B halo 46KB + A half-tap double buffer 2x16KB = 78848B -> 2 blocks/CU.
// per phase: {stage next A-half ; MFMA (preloaded B) ; prefetch next B ; barrier}
__global__ __launch_bounds__(256, 2) void kan_mfma(const __bf16* __restrict__ xt,
                                                   const __bf16* __restrict__ wc,
                                                   const float* __restrict__ zp,
                                                   float* __restrict__ out) {
    __shared__ __align__(16) char xs[2880 * 16];    // B halo: 180 pos * 256B
    __shared__ __align__(16) char asA[1024 * 16];   // A half buffer A: 16 KB
    __shared__ __align__(16) char asB[1024 * 16];   // A half buffer B: 16 KB
    const int t    = threadIdx.x;
    const int lane = t & 63, wave = t >> 6;
    const int wm = wave >> 1, wn = wave & 1;
    const int l15 = lane & 15, lq = lane >> 4;

    // XCD-chunked bijective swizzle (2048 % 8 == 0)
    const int orig = blockIdx.x;
    const int wid  = (orig & 7) * 256 + (orig >> 3);
    const int b  = wid >> 7;
    const int hy = (wid & 127) >> 3, wx = wid & 7;
    const int w0 = wx * 16, h0 = hy * 8;

    // ---- stage B halo tile once (swizzled source, linear LDS dest)
    const size_t xbase = (size_t)b * (H_ * W_ * CI2);
#pragma unroll
    for (int i = 0; i < 12; ++i) {
        const int s = i * 256 + t;
        if (s < 2880) {
            const int pos = s >> 4, q = s & 15;
            const int ih = pos / 18, iw = pos - ih * 18;
            const int gh = h0 + ih - 1, gw = w0 + iw - 1;
            const int chunk = q ^ (pos & 15);
            const void* src;
            if (gh >= 0 && gh < H_ && gw >= 0 && gw < W_)
                src = (const void*)(xt + xbase + ((size_t)(gh * W_ + gw)) * CI2 + chunk * 8);
            else
                src = (const void*)zp;
            __builtin_amdgcn_global_load_lds(
                (const __attribute__((address_space(1))) unsigned int*)src,
                (__attribute__((address_space(3))) unsigned int*)(xs + s * 16), 16, 0, 0);
        }
    }

    // ---- stage one 16KB A-half (1024 x 16B, linear both sides)
#define STAGEH_(buf, hh)                                                        \
    _Pragma("unroll")                                                           \
    for (int i = 0; i < 4; ++i) {                                               \
        const int s = i * 256 + t;                                              \
        __builtin_amdgcn_global_load_lds(                                       \
            (const __attribute__((address_space(1))) unsigned int*)              \
                (wc + (size_t)(hh) * 8192 + s * 8),                             \
            (__attribute__((address_space(3))) unsigned int*)((buf) + s * 16),  \
            16, 0, 0);                                                          \
    }

    // ---- prefetch 8 B fragments (ks = kss, kss+1; n = 0..3) for tap tp
#define LOADB2_(dst, tp, kss)                                                   \
    {                                                                           \
        const int kh_ = ((tp) * 11) >> 5;                                       \
        const int dp_ = kh_ * 18 + ((tp) - kh_ * 3);                            \
        _Pragma("unroll")                                                       \
        for (int k2 = 0; k2 < 2; ++k2)                                          \
            _Pragma("unroll")                                                   \
            for (int n = 0; n < 4; ++n) {                                       \
                const int pos_ = pos0[n] + dp_;                                 \
                const int swz_ = (((kss) + k2) * 4 + lq) ^ (pos_ & 15);         \
                dst[k2 * 4 + n] = *(const bf16x8*)(xs + pos_ * 256 + swz_ * 16);\
            }                                                                   \
    }

    // ---- 32 MFMA: A from LDS `buf`, B from register group `bfr` (ks kss,kss+1)
#define COMPUTE2_(buf, bfr, kss)                                                \
    {                                                                           \
        bf16x8 af0[4], af1[4];                                                  \
        _Pragma("unroll")                                                       \
        for (int m = 0; m < 4; ++m) {                                           \
            af0[m] = *(const bf16x8*)((buf) +                                   \
                ((wm * 4 + m) * 2 + ((kss) & 1)) * 1024 + lane * 16);           \
            af1[m] = *(const bf16x8*)((buf) +                                   \
                ((wm * 4 + m) * 2 + (((kss) + 1) & 1)) * 1024 + lane * 16);     \
        }                                                                       \
        __builtin_amdgcn_s_setprio(1);                                          \
        _Pragma("unroll")                                                       \
        for (int m = 0; m < 4; ++m)                                             \
            _Pragma("unroll")                                                   \
            for (int n = 0; n < 4; ++n)                                         \
                acc[m][n] = __builtin_amdgcn_mfma_f32_16x16x32_bf16(            \
                    af0[m], bfr[n], acc[m][n], 0, 0, 0);                        \
        _Pragma("unroll")                                                       \
        for (int m = 0; m < 4; ++m)                                             \
            _Pragma("unroll")                                                   \
            for (int n = 0; n < 4; ++n)                                         \
                acc[m][n] = __builtin_amdgcn_mfma_f32_16x16x32_bf16(            \
                    af1[m], bfr[4 + n], acc[m][n], 0, 0, 0);                    \
        __builtin_amdgcn_s_setprio(0);                                          \
    }

    STAGEH_(asA, 0);
    __syncthreads();                 // B halo + A-half 0 ready

    f32x4 acc[4][4] = {};
    int pos0[4];
#pragma unroll
    for (int n = 0; n < 4; ++n) pos0[n] = (wn * 4 + n) * 18 + l15;

    bf16x8 bP[8], bQ[8];
    LOADB2_(bP, 0, 0);               // B frags for tap0, ks{0,1}

#pragma unroll 1
    for (int tap = 0; tap < 9; ++tap) {
        // phase 0: stage A-half(tap*2+1) -> asB; MFMA ks{0,1} (A:asA, B:bP);
        //          prefetch bQ = B(tap, ks{2,3}); barrier
        STAGEH_(asB, tap * 2 + 1);
        COMPUTE2_(asA, bP, 0);
        LOADB2_(bQ, tap, 2);
        __syncthreads();

        // phase 1: stage A-half(tap*2+2) -> asA; MFMA ks{2,3} (A:asB, B:bQ);
        //          prefetch bP = B(tap+1, ks{0,1}); barrier
        if (tap < 8) STAGEH_(asA, tap * 2 + 2);
        COMPUTE2_(asB, bQ, 2);
        if (tap < 8) LOADB2_(bP, tap + 1, 0);
        __syncthreads();
    }

    // ---- epilogue: D row = co (lq*4+r), col = position (l15); 64B store rows
    float* ob = out + (size_t)b * COUT * H_ * W_;
#pragma unroll
    for (int m = 0; m < 4; ++m) {
        const int co = wm * 64 + m * 16 + lq * 4;
#pragma unroll
        for (int n = 0; n < 4; ++n) {
            const int ph = wn * 4 + n;
            float* p = ob + ((size_t)co * H_ + (h0 + ph)) * W_ + (w0 + l15);
#pragma unroll
            for (int r = 0; r < 4; ++r)
                p[(size_t)r * H_ * W_] = acc[m][n][r];
        }
    }
#undef STAGEH_
#undef LOADB2_
#undef COMPUTE2_
}

// ---------- fallback (round-0 fp32 path, used only if ws too small) ----------
#define TS   16
#define COB  8
#define TIN  18
__global__ __launch_bounds__(256) void spline_sum_kernel(const float* __restrict__ sw,
                                                         float* __restrict__ wsum) {
    int i = blockIdx.x * 256 + threadIdx.x;
    if (i < COUT * CIN * 9) {
        const float4 v = *reinterpret_cast<const float4*>(sw + (size_t)i * 4);
        wsum[i] = v.x + v.y + v.z + v.w;
    }
}
__global__ __launch_bounds__(256) void kan_conv(const float* __restrict__ x,
                                                const float* __restrict__ wsp,
                                                const float* __restrict__ wb,
                                                float* __restrict__ out) {
    __shared__ float xsm[TIN][20];
    __shared__ float ssm[TIN][20];
    const int t = threadIdx.x, tx = t & 15, ty = t >> 4;
    const int w0 = (blockIdx.x & 7) * TS, h0 = (blockIdx.x >> 3) * TS;
    const int co0 = blockIdx.y * COB, b = blockIdx.z;
    float acc[COB];
#pragma unroll
    for (int i = 0; i < COB; ++i) acc[i] = 0.f;
    const float* xb = x + (size_t)b * CIN * H_ * W_;
    for (int ci = 0; ci < CIN; ++ci) {
        __syncthreads();
        const float* xc = xb + (size_t)ci * H_ * W_;
        for (int p = t; p < TIN * TIN; p += 256) {
            int r = p / TIN, c = p - r * TIN;
            int ih = h0 + r - 1, iw = w0 + c - 1;
            float v = 0.f;
            if (ih >= 0 && ih < H_ && iw >= 0 && iw < W_) v = xc[ih * W_ + iw];
            xsm[r][c] = v;
            ssm[r][c] = v / (1.f + expf(-v));
        }
        __syncthreads();
        float xv[9], sv[9];
#pragma unroll
        for (int kh = 0; kh < 3; ++kh)
#pragma unroll
            for (int kw = 0; kw < 3; ++kw) {
                xv[kh * 3 + kw] = xsm[ty + kh][tx + kw];
                sv[kh * 3 + kw] = ssm[ty + kh][tx + kw];
            }
#pragma unroll
        for (int co = 0; co < COB; ++co) {
            const float* w1 = wsp + ((size_t)(co0 + co) * CIN + ci) * 9;
            const float* w2 = wb  + ((size_t)(co0 + co) * CIN + ci) * 9;
#pragma unroll
            for (int k = 0; k < 9; ++k)
                acc[co] += xv[k] * w1[k] + sv[k] * w2[k];
        }
    }
    const int oh = h0 + ty, ow = w0 + tx;
#pragma unroll
    for (int co = 0; co < COB; ++co)
        out[(((size_t)b * COUT + (co0 + co)) * H_ + oh) * W_ + ow] = acc[co];
}

extern "C" void kernel_launch(void* const* d_in, const int* in_sizes, int n_in,
                              void* d_out, int out_size, void* d_ws, size_t ws_size,
                              hipStream_t stream) {
    const float* x  = (const float*)d_in[0];
    const float* sw = (const float*)d_in[1];   // (COUT,CIN,3,3,4)
    const float* bw = (const float*)d_in[2];   // (COUT,CIN,3,3)
    float* out = (float*)d_out;

    if (ws_size >= WS_NEED) {
        __bf16* xt = (__bf16*)d_ws;
        __bf16* wc = (__bf16*)((char*)d_ws + XT_BYTES);
        float*  zp = (float*)((char*)d_ws + Z_OFF);
        w_prep<<<(COUT * KTOT + 255) / 256, 256, 0, stream>>>(sw, bw, wc, zp);
        xt_prep<<<dim3(2, H_, B_), 256, 0, stream>>>(x, xt);
        kan_mfma<<<dim3(2048), 256, 0, stream>>>(xt, wc, zp, out);
    } else {
        float* wsum = (float*)d_ws;
        spline_sum_kernel<<<(COUT * CIN * 9 + 255) / 256, 256, 0, stream>>>(sw, wsum);
        kan_conv<<<dim3(64, COUT / COB, B_), 256, 0, stream>>>(x, wsum, bw, out);
    }
}

// Round 17
// 103.624 us; speedup vs baseline: 1.1069x; 1.0483x over previous
//
#include <hip/hip_runtime.h>
#include <math.h>

#define B_    16
#define CIN   64
#define COUT  128
#define H_    128
#define W_    128
#define CI2   128            // 2*CIN (x ++ silu(x))
#define KTOT  1152           // 9 taps * CI2

typedef __bf16 bf16x8 __attribute__((ext_vector_type(8)));
typedef float  f32x4  __attribute__((ext_vector_type(4)));

#define XT_BYTES  ((size_t)B_ * H_ * W_ * CI2 * 2)   // 67,108,864
#define WC_BYTES  ((size_t)COUT * KTOT * 2)          // 294,912
#define Z_OFF     (XT_BYTES + WC_BYTES)
#define WS_NEED   (Z_OFF + 4096)

// ---------- prep 1: weights -> Wc, QUARTER-TAP wave-fragment order ----------
// quarter qq = (ks>>1)*18 + tap*2 + (ks&1) in [0,36); frag f = wm*4+m in [0,8)
// elem off = (qq*8 + f)*512 + lane*8 + e  -> 8KB contiguous per quarter.
__global__ __launch_bounds__(256) void w_prep(const float* __restrict__ sw,
                                              const float* __restrict__ bw,
                                              __bf16* __restrict__ wc,
                                              float* __restrict__ zp) {
    const int i = blockIdx.x * 256 + threadIdx.x;
    if (blockIdx.x == 0) zp[threadIdx.x] = 0.f;  // zeros page (1 KiB)
    if (i >= COUT * KTOT) return;
    const int co = i / KTOT, k = i - co * KTOT;
    const int tap = k >> 7, ci2 = k & 127;
    float v;
    if (ci2 < CIN) {
        const float* p = sw + ((size_t)(co * CIN + ci2) * 9 + tap) * 4;
        v = p[0] + p[1] + p[2] + p[3];
    } else {
        v = bw[(size_t)(co * CIN + (ci2 - CIN)) * 9 + tap];
    }
    const int wm = co >> 6, m = (co >> 4) & 3, l15 = co & 15;
    const int ks = ci2 >> 5, lq = (ci2 >> 3) & 3, e = ci2 & 7;
    const int qq = (ks >> 1) * 18 + tap * 2 + (ks & 1);
    const int f  = wm * 4 + m;
    const size_t off = ((size_t)(qq * 8 + f)) * 512 + (lq * 16 + l15) * 8 + e;
    wc[off] = (__bf16)v;
}

// ---------- prep 2: x (NCHW fp32) -> Xt (NHWC bf16, ci2 = x ++ silu(x)) ----------
__global__ __launch_bounds__(256) void xt_prep(const float* __restrict__ x,
                                               __bf16* __restrict__ xt) {
    __shared__ __align__(16) __bf16 tile[64][136];
    const int t  = threadIdx.x;
    const int w0 = blockIdx.x * 64;
    const int h  = blockIdx.y;
    const int b  = blockIdx.z;
    const float* xb = x + ((size_t)(b * CIN) * H_ + h) * W_ + w0;
#pragma unroll
    for (int rep = 0; rep < 16; ++rep) {
        const int idx = rep * 256 + t;
        const int ci = idx >> 6, w = idx & 63;
        const float v = xb[(size_t)ci * H_ * W_ + w];
        tile[w][ci]       = (__bf16)v;
        tile[w][CIN + ci] = (__bf16)(v / (1.f + __expf(-v)));
    }
    __syncthreads();
    __bf16* ob = xt + (((size_t)b * H_ + h) * W_ + w0) * CI2;
#pragma unroll
    for (int rep = 0; rep < 4; ++rep) {
        const int idx = rep * 256 + t;
        const int w = idx >> 4, sl = idx & 15;
        *(bf16x8*)(ob + (size_t)w * CI2 + sl * 8) = *(const bf16x8*)(&tile[w][sl * 8]);
    }
}

// ---------- main: K-split implicit-GEMM MFMA conv, high occupancy ----------
// block: 128 couts x (8h x 16w); 4 waves 2(m) x 2(n).
// LDS: B ci2-half halo 23040B + A quarter dbuf 2x8192B = 39424B -> 3-4 blocks/CU.
// outer kk = ci2-half; 36 phases: {stage A(qq+1) ; 16 MFMA ; prefetch B ; barrier}
__global__ __launch_bounds__(256, 3) void kan_mfma(const __bf16* __restrict__ xt,
                                                   const __bf16* __restrict__ wc,
                                                   const float* __restrict__ zp,
                                                   float* __restrict__ out) {
    __shared__ __align__(16) char bh[1440 * 16];    // B half-halo: 180 pos * 128B
    __shared__ __align__(16) char asA[512 * 16];    // A quarter buf A: 8 KB
    __shared__ __align__(16) char asB[512 * 16];    // A quarter buf B: 8 KB
    const int t    = threadIdx.x;
    const int lane = t & 63, wave = t >> 6;
    const int wm = wave >> 1, wn = wave & 1;
    const int l15 = lane & 15, lq = lane >> 4;

    // XCD-chunked bijective swizzle (2048 % 8 == 0)
    const int orig = blockIdx.x;
    const int wid  = (orig & 7) * 256 + (orig >> 3);
    const int b  = wid >> 7;
    const int hy = (wid & 127) >> 3, wx = wid & 7;
    const int w0 = wx * 16, h0 = hy * 8;

    const size_t xbase = (size_t)b * (H_ * W_ * CI2);

    // ---- stage B ci2-half kk: 1440 16B slots; chunk swizzle q^(pos&7)
#define STAGEB_(kk)                                                             \
    _Pragma("unroll")                                                           \
    for (int i = 0; i < 6; ++i) {                                               \
        const int s = i * 256 + t;                                              \
        if (s < 1440) {                                                         \
            const int pos = s >> 3, q = s & 7;                                  \
            const int ih = pos / 18, iw = pos - ih * 18;                        \
            const int gh = h0 + ih - 1, gw = w0 + iw - 1;                       \
            const int chunk = q ^ (pos & 7);                                    \
            const void* src;                                                    \
            if (gh >= 0 && gh < H_ && gw >= 0 && gw < W_)                       \
                src = (const void*)(xt + xbase +                                \
                      ((size_t)(gh * W_ + gw)) * CI2 + (kk) * 64 + chunk * 8);  \
            else                                                                \
                src = (const void*)zp;                                          \
            __builtin_amdgcn_global_load_lds(                                   \
                (const __attribute__((address_space(1))) unsigned int*)src,     \
                (__attribute__((address_space(3))) unsigned int*)(bh + s * 16), \
                16, 0, 0);                                                      \
        }                                                                       \
    }

    // ---- stage one 8KB A quarter (512 x 16B, linear both sides)
#define STAGEQ_(buf, qq)                                                        \
    _Pragma("unroll")                                                           \
    for (int i = 0; i < 2; ++i) {                                               \
        const int s = i * 256 + t;                                              \
        __builtin_amdgcn_global_load_lds(                                       \
            (const __attribute__((address_space(1))) unsigned int*)              \
                (wc + (size_t)(qq) * 4096 + s * 8),                             \
            (__attribute__((address_space(3))) unsigned int*)((buf) + s * 16),  \
            16, 0, 0);                                                          \
    }

    // ---- prefetch 4 B fragments for (tap tp, within-half slice ksl)
#define LOADB1_(dst, tp, ksl)                                                   \
    {                                                                           \
        const int kh_ = ((tp) * 11) >> 5;                                       \
        const int dp_ = kh_ * 18 + ((tp) - kh_ * 3);                            \
        _Pragma("unroll")                                                       \
        for (int n = 0; n < 4; ++n) {                                           \
            const int pos_ = pos0[n] + dp_;                                     \
            const int swz_ = ((ksl) * 4 + lq) ^ (pos_ & 7);                     \
            dst[n] = *(const bf16x8*)(bh + pos_ * 128 + swz_ * 16);             \
        }                                                                       \
    }

    // ---- 16 MFMA: A from LDS quarter `buf`, B from register group `bfr`
#define COMPUTE1_(buf, bfr)                                                     \
    {                                                                           \
        bf16x8 af[4];                                                           \
        _Pragma("unroll")                                                       \
        for (int m = 0; m < 4; ++m)                                             \
            af[m] = *(const bf16x8*)((buf) + (wm * 4 + m) * 1024 + lane * 16);  \
        __builtin_amdgcn_s_setprio(1);                                          \
        _Pragma("unroll")                                                       \
        for (int m = 0; m < 4; ++m)                                             \
            _Pragma("unroll")                                                   \
            for (int n = 0; n < 4; ++n)                                         \
                acc[m][n] = __builtin_amdgcn_mfma_f32_16x16x32_bf16(            \
                    af[m], bfr[n], acc[m][n], 0, 0, 0);                         \
        __builtin_amdgcn_s_setprio(0);                                          \
    }

    f32x4 acc[4][4] = {};
    int pos0[4];
#pragma unroll
    for (int n = 0; n < 4; ++n) pos0[n] = (wn * 4 + n) * 18 + l15;

    bf16x8 bP[4], bQ[4];

    STAGEB_(0);
    STAGEQ_(asA, 0);
    __syncthreads();                 // B half 0 + A quarter 0 ready
    LOADB1_(bP, 0, 0);

#pragma unroll 1
    for (int kk = 0; kk < 2; ++kk) {
        if (kk) {
            __syncthreads();         // all waves done reading bh (half 0)
            STAGEB_(1);
            __syncthreads();         // bh half 1 ready (+ pending A drained)
            LOADB1_(bP, 0, 0);
        }
#pragma unroll 1
        for (int tap = 0; tap < 9; ++tap) {
            const int qq = kk * 18 + tap * 2;
            // phase ksl=0: A in asA
            if (qq + 1 < 36) STAGEQ_(asB, qq + 1);
            COMPUTE1_(asA, bP);
            LOADB1_(bQ, tap, 1);
            __syncthreads();
            // phase ksl=1: A in asB
            if (qq + 2 < 36) STAGEQ_(asA, qq + 2);
            COMPUTE1_(asB, bQ);
            if (tap < 8) LOADB1_(bP, tap + 1, 0);
            __syncthreads();
        }
    }

    // ---- epilogue: D row = co (lq*4+r), col = position (l15); 64B store rows
    float* ob = out + (size_t)b * COUT * H_ * W_;
#pragma unroll
    for (int m = 0; m < 4; ++m) {
        const int co = wm * 64 + m * 16 + lq * 4;
#pragma unroll
        for (int n = 0; n < 4; ++n) {
            const int ph = wn * 4 + n;
            float* p = ob + ((size_t)co * H_ + (h0 + ph)) * W_ + (w0 + l15);
#pragma unroll
            for (int r = 0; r < 4; ++r)
                p[(size_t)r * H_ * W_] = acc[m][n][r];
        }
    }
#undef STAGEB_
#undef STAGEQ_
#undef LOADB1_
#undef COMPUTE1_
}

// ---------- fallback (round-0 fp32 path, used only if ws too small) ----------
#define TS   16
#define COB  8
#define TIN  18
__global__ __launch_bounds__(256) void spline_sum_kernel(const float* __restrict__ sw,
                                                         float* __restrict__ wsum) {
    int i = blockIdx.x * 256 + threadIdx.x;
    if (i < COUT * CIN * 9) {
        const float4 v = *reinterpret_cast<const float4*>(sw + (size_t)i * 4);
        wsum[i] = v.x + v.y + v.z + v.w;
    }
}
__global__ __launch_bounds__(256) void kan_conv(const float* __restrict__ x,
                                                const float* __restrict__ wsp,
                                                const float* __restrict__ wb,
                                                float* __restrict__ out) {
    __shared__ float xsm[TIN][20];
    __shared__ float ssm[TIN][20];
    const int t = threadIdx.x, tx = t & 15, ty = t >> 4;
    const int w0 = (blockIdx.x & 7) * TS, h0 = (blockIdx.x >> 3) * TS;
    const int co0 = blockIdx.y * COB, b = blockIdx.z;
    float acc[COB];
#pragma unroll
    for (int i = 0; i < COB; ++i) acc[i] = 0.f;
    const float* xb = x + (size_t)b * CIN * H_ * W_;
    for (int ci = 0; ci < CIN; ++ci) {
        __syncthreads();
        const float* xc = xb + (size_t)ci * H_ * W_;
        for (int p = t; p < TIN * TIN; p += 256) {
            int r = p / TIN, c = p - r * TIN;
            int ih = h0 + r - 1, iw = w0 + c - 1;
            float v = 0.f;
            if (ih >= 0 && ih < H_ && iw >= 0 && iw < W_) v = xc[ih * W_ + iw];
            xsm[r][c] = v;
            ssm[r][c] = v / (1.f + expf(-v));
        }
        __syncthreads();
        float xv[9], sv[9];
#pragma unroll
        for (int kh = 0; kh < 3; ++kh)
#pragma unroll
            for (int kw = 0; kw < 3; ++kw) {
                xv[kh * 3 + kw] = xsm[ty + kh][tx + kw];
                sv[kh * 3 + kw] = ssm[ty + kh][tx + kw];
            }
#pragma unroll
        for (int co = 0; co < COB; ++co) {
            const float* w1 = wsp + ((size_t)(co0 + co) * CIN + ci) * 9;
            const float* w2 = wb  + ((size_t)(co0 + co) * CIN + ci) * 9;
#pragma unroll
            for (int k = 0; k < 9; ++k)
                acc[co] += xv[k] * w1[k] + sv[k] * w2[k];
        }
    }
    const int oh = h0 + ty, ow = w0 + tx;
#pragma unroll
    for (int co = 0; co < COB; ++co)
        out[(((size_t)b * COUT + (co0 + co)) * H_ + oh) * W_ + ow] = acc[co];
}

extern "C" void kernel_launch(void* const* d_in, const int* in_sizes, int n_in,
                              void* d_out, int out_size, void* d_ws, size_t ws_size,
                              hipStream_t stream) {
    const float* x  = (const float*)d_in[0];
    const float* sw = (const float*)d_in[1];   // (COUT,CIN,3,3,4)
    const float* bw = (const float*)d_in[2];   // (COUT,CIN,3,3)
    float* out = (float*)d_out;

    if (ws_size >= WS_NEED) {
        __bf16* xt = (__bf16*)d_ws;
        __bf16* wc = (__bf16*)((char*)d_ws + XT_BYTES);
        float*  zp = (float*)((char*)d_ws + Z_OFF);
        w_prep<<<(COUT * KTOT + 255) / 256, 256, 0, stream>>>(sw, bw, wc, zp);
        xt_prep<<<dim3(2, H_, B_), 256, 0, stream>>>(x, xt);
        kan_mfma<<<dim3(2048), 256, 0, stream>>>(xt, wc, zp, out);
    } else {
        float* wsum = (float*)d_ws;
        spline_sum_kernel<<<(COUT * CIN * 9 + 255) / 256, 256, 0, stream>>>(sw, wsum);
        kan_conv<<<dim3(64, COUT / COB, B_), 256, 0, stream>>>(x, wsum, bw, out);
    }
}